// Round 5
// baseline (808.759 us; speedup 1.0000x reference)
//
#include <hip/hip_runtime.h>
#include <hip/hip_bf16.h>
#include <cstdint>
#include <cstddef>

// MotionNet decoder: B=16384, STATE=524, IENC=256, ZD=32, H=256, E=5, HG=256
// Round 5: register-prefetch double buffering (global->VGPR issued before the
// compute phase, VGPR->LDS store next iteration) — real overlap that the
// vmcnt(0)-before-barrier drain can't serialize. convert_I fused into inet1.

#define BATCH 16384

typedef __attribute__((ext_vector_type(8))) short short8;  // 8 bf16 (4 VGPRs)
typedef __attribute__((ext_vector_type(4))) float f32x4;   // MFMA accumulator
typedef unsigned short u16;
typedef unsigned int u32;

__device__ __forceinline__ float bf2f(u16 u) {
  union { float f; u32 i; } v; v.i = ((u32)u) << 16; return v.f;
}
__device__ __forceinline__ u16 f2bf(float f) {
  union { float f; u32 i; } v; v.f = f;
  u32 x = v.i;
  return (u16)((x + 0x7fffu + ((x >> 16) & 1u)) >> 16);  // RNE
}
__device__ __forceinline__ u16 load_bf(const void* p, long i, int f32) {
  return f32 ? f2bf(((const float*)p)[i]) : ((const u16*)p)[i];
}
__device__ __forceinline__ float elu_f(float x) { return x > 0.f ? x : expm1f(x); }

// pack 8 fp32 (two uint4-reinterpreted float4s) -> 8 bf16 in one uint4
__device__ __forceinline__ uint4 cvt8(uint4 a, uint4 b) {
  const float* fa = (const float*)&a;
  const float* fb = (const float*)&b;
  union { u16 r[8]; uint4 v; } u;
  u.r[0] = f2bf(fa[0]); u.r[1] = f2bf(fa[1]); u.r[2] = f2bf(fa[2]); u.r[3] = f2bf(fa[3]);
  u.r[4] = f2bf(fb[0]); u.r[5] = f2bf(fb[1]); u.r[6] = f2bf(fb[2]); u.r[7] = f2bf(fb[3]);
  return u.v;
}

// LDS tile layout (verified round 4): rows of 32 u16; 16B chunk q of row r at
// chunk slot q^((r>>1)&3). Staging lane l covers global chunk (l&3)^((l>>3)&3)
// of row seg+(l>>2), stored at lds_base + l*16B.
__device__ __forceinline__ int swz(int row, int q) { return q ^ ((row >> 1) & 3); }

// ---------------------------------------------------------------------------
// dtype detection: bf16-pair storage -> word bits 7..14 = low element's
// exponent (near 127 for N(0,1)); fp32 -> uniform mantissa bits.
// flag: 1 = fp32 storage, 0 = bf16 storage.
// ---------------------------------------------------------------------------
__global__ __launch_bounds__(256) void detect_dtype(const u32* __restrict__ zr,
                                                    int* __restrict__ flag)
{
  __shared__ int cnt;
  if (threadIdx.x == 0) cnt = 0;
  __syncthreads();
  u32 w = zr[threadIdx.x];
  int e = (w >> 7) & 0xFF;
  if (e >= 112 && e <= 142) atomicAdd(&cnt, 1);
  __syncthreads();
  if (threadIdx.x == 0) *flag = (cnt < 128) ? 1 : 0;
}

// ---------------------------------------------------------------------------
// prep: h0[B,832] = [z(32) | p_prev(524) | (ienc by inet3) | 0-pad(20)]
//       h1c/h2c[B,288] cols 0..31 = z.  2-D grid: y=row, x*256+tid=col.
// Block (0,0) also canonicalizes small tensors into smallc.
// ---------------------------------------------------------------------------
__global__ __launch_bounds__(256) void prep_kernel(
    const void* __restrict__ z, const void* __restrict__ p,
    const int* __restrict__ flagp,
    u16* __restrict__ h0, u16* __restrict__ h1c, u16* __restrict__ h2c,
    const void* ib1, const void* ib2, const void* ib3,
    const void* gb1, const void* gb2, const void* gb3,
    const void* gw3, const void* bl1, const void* bl2, const void* bl3,
    u16* __restrict__ smallc)
{
  const int f32 = *flagp;
  const int b = blockIdx.y;
  const int c = blockIdx.x * 256 + threadIdx.x;
  if (blockIdx.y == 0 && blockIdx.x == 0) {
    for (long j = threadIdx.x; j < 7100; j += 256) {
      u16 v;
      if      (j < 256)  v = load_bf(ib1, j,        f32);
      else if (j < 512)  v = load_bf(ib2, j - 256,  f32);
      else if (j < 768)  v = load_bf(ib3, j - 512,  f32);
      else if (j < 1024) v = load_bf(gb1, j - 768,  f32);
      else if (j < 1152) v = load_bf(gb2, j - 1024, f32);
      else if (j < 1280) v = (j - 1152 < 5) ? load_bf(gb3, j - 1152, f32) : (u16)0;
      else if (j < 1920) v = load_bf(gw3, j - 1280, f32);
      else if (j < 3200) v = load_bf(bl1, j - 1920, f32);
      else if (j < 4480) v = load_bf(bl2, j - 3200, f32);
      else               v = load_bf(bl3, j - 4480, f32);
      smallc[j] = v;
    }
  }
  if (c >= 832) return;
  const long i = (long)b * 832 + c;
  if (c < 32) {
    u16 v = load_bf(z, (long)b * 32 + c, f32);
    h0[i] = v;
    h1c[(long)b * 288 + c] = v;
    h2c[(long)b * 288 + c] = v;
  } else if (c < 556) {
    h0[i] = load_bf(p, (long)b * 524 + (c - 32), f32);
  } else if (c >= 812) {
    h0[i] = 0;
  }
}

// ---------------------------------------------------------------------------
// All 8 weight transposes fused: out[e][n][k] = in[e][k][n] or 0-pad.
// ---------------------------------------------------------------------------
struct TPSeg { long end; int K, N, Kp, Np; };

__global__ __launch_bounds__(256) void transpose_all(
    const int* __restrict__ flagp,
    const void* s0, const void* s1, const void* s2, const void* s3,
    const void* s4, const void* s5, const void* s6, const void* s7,
    u16* d0, u16* d1, u16* d2, u16* d3, u16* d4, u16* d5, u16* d6, u16* d7)
{
  const TPSeg seg[8] = {
    {  524288, 2048, 256, 2048, 256 },
    {  589824,  256, 256,  256, 256 },
    {  655360,  256, 256,  256, 256 },
    {  802816,  556, 256,  576, 256 },
    {  835584,  256, 128,  256, 128 },
    { 1900544,  812, 256,  832, 256 },   // E=5
    { 2269184,  288, 256,  288, 256 },   // E=5
    { 3098624,  288, 524,  288, 576 },   // E=5
  };
  const void* const srcs[8] = { s0, s1, s2, s3, s4, s5, s6, s7 };
  u16* const dsts[8] = { d0, d1, d2, d3, d4, d5, d6, d7 };
  const int f32 = *flagp;
  const long total = 3098624;
  const long stride = (long)gridDim.x * blockDim.x;
  for (long i = (long)blockIdx.x * blockDim.x + threadIdx.x; i < total; i += stride) {
    int s = 0;
    long base = 0;
    while (i >= seg[s].end) { base = seg[s].end; ++s; }
    const long j = i - base;
    const int Kp = seg[s].Kp, Np = seg[s].Np, K = seg[s].K, N = seg[s].N;
    const int k = (int)(j % Kp);
    const long t = j / Kp;
    const int n = (int)(t % Np);
    const int e = (int)(t / Np);
    u16 v = 0;
    if (k < K && n < N) v = load_bf(srcs[s], (long)e * K * N + (long)k * N + n, f32);
    dsts[s][j] = v;
  }
}

// ---------------------------------------------------------------------------
// Generic GEMM: C[M,N] = elu(A[M,K] @ W[K,N] + bias), W transposed [N][K].
// Block 128x128, 4 waves 2x2, wave tile 64x64 = 4x4 MFMA 16x16x32.
// Register-prefetch pipeline: loads for tile k+1 issued before compute(k);
// VGPR->LDS stores at top of iteration k+1 (vmcnt wait lands after compute).
// ACONV: A may be raw fp32 input (runtime flag), converted at store time.
// ---------------------------------------------------------------------------
template<bool ELU, bool ACONV>
__global__ __launch_bounds__(256) void gemm128(
    const void* __restrict__ Av, int lda,
    const u16* __restrict__ Wt, int ldw,
    const u16* __restrict__ bias,
    u16* __restrict__ C, int ldc, int col_off, int K,
    const int* __restrict__ flagp)
{
  __shared__ __align__(16) u16 sA[128 * 32];
  __shared__ __align__(16) u16 sB[128 * 32];

  const int tid  = threadIdx.x;
  const int bm   = blockIdx.x, bn = blockIdx.y;
  const int lane = tid & 63, wave = tid >> 6;
  const int wm = (wave & 1) * 64, wn = (wave >> 1) * 64;
  const int lrow = lane & 15, lq = lane >> 4;
  const int f32 = ACONV ? *flagp : 0;

  // staging: wave w covers rows 32w..32w+31 (two 16-row segments)
  const int srow0 = 32 * wave + (lane >> 2);
  const int sq    = (lane & 3) ^ ((lane >> 3) & 3);   // swizzled global chunk
  const u16*  A16 = (const u16*)Av  + (size_t)(bm * 128 + srow0) * lda + sq * 8;
  const float* A32 = (const float*)Av + (size_t)(bm * 128 + srow0) * lda + sq * 8;
  const u16* Wg = Wt + (size_t)(bn * 128 + srow0) * ldw + sq * 8;
  u16* lA = sA + wave * 1024 + lane * 8;   // lane's 16B slot (seg0); seg1 at +512
  u16* lB = sB + wave * 1024 + lane * 8;

  uint4 ra0, ra1, ra2, ra3, rb0, rb1;
  if (f32) {
    ra0 = *(const uint4*)(A32);
    ra1 = *(const uint4*)(A32 + 4);
    ra2 = *(const uint4*)(A32 + (size_t)16 * lda);
    ra3 = *(const uint4*)(A32 + (size_t)16 * lda + 4);
  } else {
    ra0 = *(const uint4*)(A16);
    ra2 = *(const uint4*)(A16 + (size_t)16 * lda);
    ra1 = ra3 = ra0;  // keep defined
  }
  rb0 = *(const uint4*)(Wg);
  rb1 = *(const uint4*)(Wg + (size_t)16 * ldw);

  f32x4 acc[4][4] = {};

  for (int k0 = 0; k0 < K; k0 += 32) {
    __syncthreads();                        // prev tile's readers done
    if (f32) {
      *(uint4*)lA         = cvt8(ra0, ra1);
      *(uint4*)(lA + 512) = cvt8(ra2, ra3);
    } else {
      *(uint4*)lA         = ra0;
      *(uint4*)(lA + 512) = ra2;
    }
    *(uint4*)lB         = rb0;
    *(uint4*)(lB + 512) = rb1;
    __syncthreads();                        // tile k0 visible

    const int k1 = k0 + 32;
    if (k1 < K) {                           // prefetch tile k1 (overlaps MFMA)
      if (f32) {
        ra0 = *(const uint4*)(A32 + k1);
        ra1 = *(const uint4*)(A32 + k1 + 4);
        ra2 = *(const uint4*)(A32 + (size_t)16 * lda + k1);
        ra3 = *(const uint4*)(A32 + (size_t)16 * lda + k1 + 4);
      } else {
        ra0 = *(const uint4*)(A16 + k1);
        ra2 = *(const uint4*)(A16 + (size_t)16 * lda + k1);
      }
      rb0 = *(const uint4*)(Wg + k1);
      rb1 = *(const uint4*)(Wg + (size_t)16 * ldw + k1);
    }

    short8 a[4], b[4];
#pragma unroll
    for (int i = 0; i < 4; ++i) {
      const int r = wm + i * 16 + lrow;
      a[i] = *(const short8*)(sA + r * 32 + swz(r, lq) * 8);
    }
#pragma unroll
    for (int i = 0; i < 4; ++i) {
      const int r = wn + i * 16 + lrow;
      b[i] = *(const short8*)(sB + r * 32 + swz(r, lq) * 8);
    }
#pragma unroll
    for (int mi = 0; mi < 4; ++mi)
#pragma unroll
      for (int ni = 0; ni < 4; ++ni)
        acc[mi][ni] = __builtin_amdgcn_mfma_f32_16x16x32_bf16(a[mi], b[ni], acc[mi][ni], 0, 0, 0);
  }

#pragma unroll
  for (int ni = 0; ni < 4; ++ni) {
    const int col = bn * 128 + wn + ni * 16 + lrow;
    const float bv = bf2f(bias[col]);
#pragma unroll
    for (int mi = 0; mi < 4; ++mi) {
#pragma unroll
      for (int r = 0; r < 4; ++r) {
        const int row = bm * 128 + wm + mi * 16 + lq * 4 + r;
        float v = acc[mi][ni][r] + bv;
        if (ELU) v = elu_f(v);
        C[(size_t)row * ldc + col_off + col] = f2bf(v);
      }
    }
  }
}

// ---------------------------------------------------------------------------
// gating layer 3 + softmax: omega[B,5] fp32 = softmax(g2[B,128]@gw3 + gb3)
// ---------------------------------------------------------------------------
__global__ __launch_bounds__(256) void gating3_kernel(
    const u16* __restrict__ g2, const u16* __restrict__ gw3c,
    const u16* __restrict__ gb3c, float* __restrict__ omega)
{
  const int wid  = (blockIdx.x << 2) + (threadIdx.x >> 6);
  const int lane = threadIdx.x & 63;
  const u32 gp = *(const u32*)(g2 + (size_t)wid * 128 + lane * 2);
  const float x0 = bf2f((u16)(gp & 0xffffu));
  const float x1 = bf2f((u16)(gp >> 16));
  float acc[5];
#pragma unroll
  for (int e = 0; e < 5; ++e)
    acc[e] = x0 * bf2f(gw3c[(lane * 2) * 5 + e]) + x1 * bf2f(gw3c[(lane * 2 + 1) * 5 + e]);
#pragma unroll
  for (int off = 1; off < 64; off <<= 1) {
#pragma unroll
    for (int e = 0; e < 5; ++e) acc[e] += __shfl_xor(acc[e], off);
  }
  if (lane == 0) {
    float t[5], m = -1e30f;
#pragma unroll
    for (int e = 0; e < 5; ++e) { t[e] = acc[e] + bf2f(gb3c[e]); m = fmaxf(m, t[e]); }
    float s = 0.f;
#pragma unroll
    for (int e = 0; e < 5; ++e) { t[e] = expf(t[e] - m); s += t[e]; }
    const float inv = 1.f / s;
#pragma unroll
    for (int e = 0; e < 5; ++e) omega[(size_t)wid * 5 + e] = t[e] * inv;
  }
}

// ---------------------------------------------------------------------------
// MoE GEMM: out[b,n] = act( sum_e omega[b,e] * ((A@W_e)[n] + bias_e[n]) )
// Block 64x64, waves 2x2 (wave tile 32x32, 2x2 MFMA per expert), A staged once
// per K-step, reused by 5 experts. Register-prefetch pipeline as in gemm128.
// ---------------------------------------------------------------------------
template<bool ELU>
__global__ __launch_bounds__(256) void moe_gemm(
    const u16* __restrict__ A, int lda,
    const u16* __restrict__ Wt, int ldw, long wstride_e,
    const u16* __restrict__ bias, int bias_n,
    const float* __restrict__ omega,
    void* __restrict__ C, int ldc, int col_off, int n_store, int K,
    const int* __restrict__ flagp, int is_final)
{
  __shared__ __align__(16) u16 sA[64 * 32];
  __shared__ __align__(16) u16 sW[5][64 * 32];
  __shared__ float som[64 * 5];
  __shared__ float sbias[5][64];

  const int tid  = threadIdx.x;
  const int bm   = blockIdx.x, bn = blockIdx.y;
  const int lane = tid & 63, wave = tid >> 6;
  const int wm = (wave & 1) * 32, wn = (wave >> 1) * 32;
  const int lrow = lane & 15, lq = lane >> 4;
  const int f32out = is_final ? *flagp : 0;

  const int srow = 16 * wave + (lane >> 2);
  const int sq   = (lane & 3) ^ ((lane >> 3) & 3);
  const u16* Ag = A  + (size_t)(bm * 64 + srow) * lda + sq * 8;
  const u16* Wg = Wt + (size_t)(bn * 64 + srow) * ldw + sq * 8;
  const int lslot = wave * 512 + lane * 8;   // lane's 16B staging slot

  // prologue prefetch (issued before the LDS om/bias fill to stay in flight)
  uint4 qa = *(const uint4*)(Ag);
  uint4 qw[5];
#pragma unroll
  for (int e = 0; e < 5; ++e) qw[e] = *(const uint4*)(Wg + e * wstride_e);

  for (int t = tid; t < 320; t += 256) {   // 320 items on 256 threads
    som[t] = omega[(size_t)(bm * 64) * 5 + t];
    const int e = t >> 6, c = t & 63;
    const int col = bn * 64 + c;
    sbias[e][c] = (col < bias_n) ? bf2f(bias[(size_t)e * bias_n + col]) : 0.f;
  }

  f32x4 acc[5][2][2] = {};

  for (int k0 = 0; k0 < K; k0 += 32) {
    __syncthreads();
    *(uint4*)(sA + lslot) = qa;
#pragma unroll
    for (int e = 0; e < 5; ++e) *(uint4*)(sW[e] + lslot) = qw[e];
    __syncthreads();

    const int k1 = k0 + 32;
    if (k1 < K) {                          // prefetch next tile (overlaps MFMA)
      qa = *(const uint4*)(Ag + k1);
#pragma unroll
      for (int e = 0; e < 5; ++e) qw[e] = *(const uint4*)(Wg + e * wstride_e + k1);
    }

    const int ra0 = wm + lrow, ra1 = ra0 + 16;
    short8 a0 = *(const short8*)(sA + ra0 * 32 + swz(ra0, lq) * 8);
    short8 a1 = *(const short8*)(sA + ra1 * 32 + swz(ra1, lq) * 8);
    const int rb0 = wn + lrow, rb1 = rb0 + 16;
    const int ob0 = rb0 * 32 + swz(rb0, lq) * 8;
    const int ob1 = rb1 * 32 + swz(rb1, lq) * 8;
#pragma unroll
    for (int e = 0; e < 5; ++e) {
      short8 b0 = *(const short8*)(sW[e] + ob0);
      short8 b1 = *(const short8*)(sW[e] + ob1);
      acc[e][0][0] = __builtin_amdgcn_mfma_f32_16x16x32_bf16(a0, b0, acc[e][0][0], 0, 0, 0);
      acc[e][0][1] = __builtin_amdgcn_mfma_f32_16x16x32_bf16(a0, b1, acc[e][0][1], 0, 0, 0);
      acc[e][1][0] = __builtin_amdgcn_mfma_f32_16x16x32_bf16(a1, b0, acc[e][1][0], 0, 0, 0);
      acc[e][1][1] = __builtin_amdgcn_mfma_f32_16x16x32_bf16(a1, b1, acc[e][1][1], 0, 0, 0);
    }
  }

#pragma unroll
  for (int mi = 0; mi < 2; ++mi) {
#pragma unroll
    for (int r = 0; r < 4; ++r) {
      const int rl = wm + mi * 16 + lq * 4 + r;
      const int row = bm * 64 + rl;
      float om[5];
#pragma unroll
      for (int e = 0; e < 5; ++e) om[e] = som[rl * 5 + e];
#pragma unroll
      for (int ni = 0; ni < 2; ++ni) {
        const int c = wn + ni * 16 + lrow;
        const int col = bn * 64 + c;
        if (col < n_store) {
          float v = 0.f;
#pragma unroll
          for (int e = 0; e < 5; ++e) v += om[e] * (acc[e][mi][ni][r] + sbias[e][c]);
          if (ELU) v = elu_f(v);
          const size_t idx = (size_t)row * ldc + col_off + col;
          if (f32out) ((float*)C)[idx] = v;
          else        ((u16*)C)[idx]   = f2bf(v);
        }
      }
    }
  }
}

// ---------------------------------------------------------------------------
extern "C" void kernel_launch(void* const* d_in, const int* in_sizes, int n_in,
                              void* d_out, int out_size, void* d_ws, size_t ws_size,
                              hipStream_t stream)
{
  const void* z    = d_in[0];
  const void* pprev= d_in[1];
  const void* I    = d_in[2];
  const void* gw1  = d_in[3];
  const void* gb1  = d_in[4];
  const void* gw2  = d_in[5];
  const void* gb2  = d_in[6];
  const void* gw3  = d_in[7];
  const void* gb3  = d_in[8];
  const void* iw1  = d_in[9];
  const void* ib1  = d_in[10];
  const void* iw2  = d_in[11];
  const void* ib2  = d_in[12];
  const void* iw3  = d_in[13];
  const void* ib3  = d_in[14];
  const void* wl1  = d_in[15];
  const void* bl1  = d_in[16];
  const void* wl2  = d_in[17];
  const void* bl2  = d_in[18];
  const void* wl3  = d_in[19];
  const void* bl3  = d_in[20];

  char* base = (char*)d_ws;
  size_t off = 0;
  auto alloc = [&](size_t bytes) -> void* {
    void* p = base + off;
    off = (off + bytes + 255) & ~(size_t)255;
    return p;
  };

  const size_t B = BATCH;
  int* flagp   = (int*)alloc(256);
  u16* h0      = (u16*)alloc(B * 832 * 2);   // [z | p_prev | ienc | pad0]
  u16* h1c     = (u16*)alloc(B * 288 * 2);   // [z | h1]
  u16* h2c     = (u16*)alloc(B * 288 * 2);   // [z | h2]
  u16* i1      = (u16*)alloc(B * 256 * 2);
  u16* i2      = (u16*)alloc(B * 256 * 2);
  float* omega = (float*)alloc(B * 5 * 4);
  u16* smallc  = (u16*)alloc(7100 * 2);
  u16* iw1t = (u16*)alloc((size_t)256 * 2048 * 2);
  u16* iw2t = (u16*)alloc((size_t)256 * 256 * 2);
  u16* iw3t = (u16*)alloc((size_t)256 * 256 * 2);
  u16* gw1t = (u16*)alloc((size_t)256 * 576 * 2);
  u16* gw2t = (u16*)alloc((size_t)128 * 256 * 2);
  u16* wl1t = (u16*)alloc((size_t)5 * 256 * 832 * 2);
  u16* wl2t = (u16*)alloc((size_t)5 * 256 * 288 * 2);
  u16* wl3t = (u16*)alloc((size_t)5 * 576 * 288 * 2);
  u16* g1 = i1;  // INet temporaries dead by gating time
  u16* g2 = i2;
  (void)in_sizes; (void)n_in; (void)out_size; (void)ws_size;

  u16* ib1c = smallc + 0,   *ib2c = smallc + 256, *ib3c = smallc + 512;
  u16* gb1c = smallc + 768, *gb2c = smallc + 1024, *gb3c = smallc + 1152;
  u16* gw3c = smallc + 1280;
  u16* bl1c = smallc + 1920, *bl2c = smallc + 3200, *bl3c = smallc + 4480;

  // ---- dtype detect + canonicalize ----
  detect_dtype<<<1, 256, 0, stream>>>((const u32*)z, flagp);
  prep_kernel<<<dim3(4, BATCH), 256, 0, stream>>>(z, pprev, flagp, h0, h1c, h2c,
      ib1, ib2, ib3, gb1, gb2, gb3, gw3, bl1, bl2, bl3, smallc);
  transpose_all<<<3072, 256, 0, stream>>>(flagp,
      iw1, iw2, iw3, gw1, gw2, wl1, wl2, wl3,
      iw1t, iw2t, iw3t, gw1t, gw2t, wl1t, wl2t, wl3t);

  // ---- INet: I(2048, raw dtype) -> 256 -> 256 -> 256, into h0 cols 556..811
  gemm128<true, true ><<<dim3(BATCH/128, 2), 256, 0, stream>>>(I,  2048, iw1t, 2048, ib1c, i1, 256, 0,   2048, flagp);
  gemm128<true, false><<<dim3(BATCH/128, 2), 256, 0, stream>>>(i1, 256,  iw2t, 256,  ib2c, i2, 256, 0,   256,  flagp);
  gemm128<true, false><<<dim3(BATCH/128, 2), 256, 0, stream>>>(i2, 256,  iw3t, 256,  ib3c, h0, 832, 556, 256,  flagp);

  // ---- Gating: [z|p_prev](556, padded 576) -> 256 -> 128 -> softmax(5) ----
  gemm128<true, false><<<dim3(BATCH/128, 2), 256, 0, stream>>>(h0, 832, gw1t, 576, gb1c, g1, 256, 0, 576, flagp);
  gemm128<true, false><<<dim3(BATCH/128, 1), 256, 0, stream>>>(g1, 256, gw2t, 256, gb2c, g2, 128, 0, 256, flagp);
  gating3_kernel<<<BATCH/4, 256, 0, stream>>>(g2, gw3c, gb3c, omega);

  // ---- MoE layers ----
  moe_gemm<true><<<dim3(BATCH/64, 4), 256, 0, stream>>>(
      h0, 832, wl1t, 832, (long)256 * 832, bl1c, 256, omega, h1c, 288, 32, 256, 832, flagp, 0);
  moe_gemm<true><<<dim3(BATCH/64, 4), 256, 0, stream>>>(
      h1c, 288, wl2t, 288, (long)256 * 288, bl2c, 256, omega, h2c, 288, 32, 256, 288, flagp, 0);
  moe_gemm<false><<<dim3(BATCH/64, 9), 256, 0, stream>>>(
      h2c, 288, wl3t, 288, (long)576 * 288, bl3c, 524, omega, d_out, 524, 0, 524, 288, flagp, 1);
}

// Round 6
// 589.577 us; speedup vs baseline: 1.3718x; 1.3718x over previous
//
#include <hip/hip_runtime.h>
#include <hip/hip_bf16.h>
#include <cstdint>
#include <cstddef>

// MotionNet decoder: B=16384, STATE=524, IENC=256, ZD=32, H=256, E=5, HG=256
// Round 6: moe_gemm rebuilt with 128x64 block tile / 64x32 wave tile (LDS
// reads per MFMA 0.6 -> 0.35) + __launch_bounds__(256,2) for the 160-VGPR
// accumulator set (round-5 spill fix). gemm128/convert_I = round-4 forms.

#define BATCH 16384

typedef __attribute__((ext_vector_type(8))) short short8;  // 8 bf16 (4 VGPRs)
typedef __attribute__((ext_vector_type(4))) float f32x4;   // MFMA accumulator
typedef unsigned short u16;
typedef unsigned int u32;

typedef __attribute__((address_space(3))) void lds_t;
typedef __attribute__((address_space(1))) void gmem_t;

// async global->LDS DMA, 16 B/lane. LDS dest = wave-uniform base + lane*16.
__device__ __forceinline__ void gload16(const u16* g, u16* l) {
  __builtin_amdgcn_global_load_lds((gmem_t*)(u16*)g, (lds_t*)l, 16, 0, 0);
}

__device__ __forceinline__ float bf2f(u16 u) {
  union { float f; u32 i; } v; v.i = ((u32)u) << 16; return v.f;
}
__device__ __forceinline__ u16 f2bf(float f) {
  union { float f; u32 i; } v; v.f = f;
  u32 x = v.i;
  return (u16)((x + 0x7fffu + ((x >> 16) & 1u)) >> 16);  // RNE
}
__device__ __forceinline__ u16 load_bf(const void* p, long i, int f32) {
  return f32 ? f2bf(((const float*)p)[i]) : ((const u16*)p)[i];
}
__device__ __forceinline__ float elu_f(float x) { return x > 0.f ? x : expm1f(x); }

// LDS tile layout (validated round 4): rows of 32 u16 (64 B); 16B chunk q of
// row r lives at chunk slot q^((r>>1)&3). Staging lane l covers global chunk
// (l&3)^((l>>3)&3) of row seg+(l>>2); DMA lands it at base + l*16B = correct.
__device__ __forceinline__ int swz(int row, int q) { return q ^ ((row >> 1) & 3); }

// ---------------------------------------------------------------------------
// dtype detection: bf16-pair storage -> word bits 7..14 = low element's
// exponent (near 127 for N(0,1)); fp32 -> uniform mantissa bits.
// flag: 1 = fp32 storage, 0 = bf16 storage.
// ---------------------------------------------------------------------------
__global__ __launch_bounds__(256) void detect_dtype(const u32* __restrict__ zr,
                                                    int* __restrict__ flag)
{
  __shared__ int cnt;
  if (threadIdx.x == 0) cnt = 0;
  __syncthreads();
  u32 w = zr[threadIdx.x];
  int e = (w >> 7) & 0xFF;
  if (e >= 112 && e <= 142) atomicAdd(&cnt, 1);
  __syncthreads();
  if (threadIdx.x == 0) *flag = (cnt < 128) ? 1 : 0;
}

// ---------------------------------------------------------------------------
// prep: h0[B,832] = [z(32) | p_prev(524) | (ienc by inet3) | 0-pad(20)]
//       h1c/h2c[B,288] cols 0..31 = z.  2-D grid: y=row, x*256+tid=col.
// Block (0,0) also canonicalizes small tensors into smallc.
// ---------------------------------------------------------------------------
__global__ __launch_bounds__(256) void prep_kernel(
    const void* __restrict__ z, const void* __restrict__ p,
    const int* __restrict__ flagp,
    u16* __restrict__ h0, u16* __restrict__ h1c, u16* __restrict__ h2c,
    const void* ib1, const void* ib2, const void* ib3,
    const void* gb1, const void* gb2, const void* gb3,
    const void* gw3, const void* bl1, const void* bl2, const void* bl3,
    u16* __restrict__ smallc)
{
  const int f32 = *flagp;
  const int b = blockIdx.y;
  const int c = blockIdx.x * 256 + threadIdx.x;
  if (blockIdx.y == 0 && blockIdx.x == 0) {
    for (long j = threadIdx.x; j < 7100; j += 256) {
      u16 v;
      if      (j < 256)  v = load_bf(ib1, j,        f32);
      else if (j < 512)  v = load_bf(ib2, j - 256,  f32);
      else if (j < 768)  v = load_bf(ib3, j - 512,  f32);
      else if (j < 1024) v = load_bf(gb1, j - 768,  f32);
      else if (j < 1152) v = load_bf(gb2, j - 1024, f32);
      else if (j < 1280) v = (j - 1152 < 5) ? load_bf(gb3, j - 1152, f32) : (u16)0;
      else if (j < 1920) v = load_bf(gw3, j - 1280, f32);
      else if (j < 3200) v = load_bf(bl1, j - 1920, f32);
      else if (j < 4480) v = load_bf(bl2, j - 3200, f32);
      else               v = load_bf(bl3, j - 4480, f32);
      smallc[j] = v;
    }
  }
  if (c >= 832) return;
  const long i = (long)b * 832 + c;
  if (c < 32) {
    u16 v = load_bf(z, (long)b * 32 + c, f32);
    h0[i] = v;
    h1c[(long)b * 288 + c] = v;
    h2c[(long)b * 288 + c] = v;
  } else if (c < 556) {
    h0[i] = load_bf(p, (long)b * 524 + (c - 32), f32);
  } else if (c >= 812) {
    h0[i] = 0;
  }
}

// ---------------------------------------------------------------------------
// I[B,2048] -> canonical bf16, 8 elements/thread
// ---------------------------------------------------------------------------
__global__ __launch_bounds__(256) void convert_I(
    const void* __restrict__ I, const int* __restrict__ flagp,
    u16* __restrict__ out)
{
  const int f32 = *flagp;
  const long total8 = (long)BATCH * 2048 / 8;
  const long stride = (long)gridDim.x * blockDim.x;
  for (long t = (long)blockIdx.x * blockDim.x + threadIdx.x; t < total8; t += stride) {
    if (f32) {
      const float4* src = (const float4*)I;
      float4 a = src[t * 2], b = src[t * 2 + 1];
      union { u16 r[8]; uint4 v; } u;
      u.r[0] = f2bf(a.x); u.r[1] = f2bf(a.y); u.r[2] = f2bf(a.z); u.r[3] = f2bf(a.w);
      u.r[4] = f2bf(b.x); u.r[5] = f2bf(b.y); u.r[6] = f2bf(b.z); u.r[7] = f2bf(b.w);
      *(uint4*)(out + t * 8) = u.v;
    } else {
      *(uint4*)(out + t * 8) = ((const uint4*)I)[t];
    }
  }
}

// ---------------------------------------------------------------------------
// All 8 weight transposes fused: out[e][n][k] = in[e][k][n] or 0-pad.
// ---------------------------------------------------------------------------
struct TPSeg { long end; int K, N, Kp, Np; };

__global__ __launch_bounds__(256) void transpose_all(
    const int* __restrict__ flagp,
    const void* s0, const void* s1, const void* s2, const void* s3,
    const void* s4, const void* s5, const void* s6, const void* s7,
    u16* d0, u16* d1, u16* d2, u16* d3, u16* d4, u16* d5, u16* d6, u16* d7)
{
  const TPSeg seg[8] = {
    {  524288, 2048, 256, 2048, 256 },
    {  589824,  256, 256,  256, 256 },
    {  655360,  256, 256,  256, 256 },
    {  802816,  556, 256,  576, 256 },
    {  835584,  256, 128,  256, 128 },
    { 1900544,  812, 256,  832, 256 },   // E=5
    { 2269184,  288, 256,  288, 256 },   // E=5
    { 3098624,  288, 524,  288, 576 },   // E=5
  };
  const void* const srcs[8] = { s0, s1, s2, s3, s4, s5, s6, s7 };
  u16* const dsts[8] = { d0, d1, d2, d3, d4, d5, d6, d7 };
  const int f32 = *flagp;
  const long total = 3098624;
  const long stride = (long)gridDim.x * blockDim.x;
  for (long i = (long)blockIdx.x * blockDim.x + threadIdx.x; i < total; i += stride) {
    int s = 0;
    long base = 0;
    while (i >= seg[s].end) { base = seg[s].end; ++s; }
    const long j = i - base;
    const int Kp = seg[s].Kp, Np = seg[s].Np, K = seg[s].K, N = seg[s].N;
    const int k = (int)(j % Kp);
    const long t = j / Kp;
    const int n = (int)(t % Np);
    const int e = (int)(t / Np);
    u16 v = 0;
    if (k < K && n < N) v = load_bf(srcs[s], (long)e * K * N + (long)k * N + n, f32);
    dsts[s][j] = v;
  }
}

// ---------------------------------------------------------------------------
// Generic GEMM (round-4 form): C[M,N] = elu(A[M,K] @ W[K,N] + bias), W [N][K].
// Block 128x128, 4 waves 2x2, wave tile 64x64 = 4x4 MFMA 16x16x32.
// Staging: global_load_lds x4/thread per BK=32 step; swizzled LDS.
// ---------------------------------------------------------------------------
template<bool ELU>
__global__ __launch_bounds__(256) void gemm128(
    const u16* __restrict__ A, int lda,
    const u16* __restrict__ Wt, int ldw,
    const u16* __restrict__ bias,
    u16* __restrict__ C, int ldc, int col_off, int K)
{
  __shared__ __align__(16) u16 sA[128 * 32];
  __shared__ __align__(16) u16 sB[128 * 32];

  const int tid  = threadIdx.x;
  const int bm   = blockIdx.x, bn = blockIdx.y;
  const int lane = tid & 63, wave = tid >> 6;
  const int wm = (wave & 1) * 64, wn = (wave >> 1) * 64;
  const int lrow = lane & 15, lq = lane >> 4;

  const int srow0 = 32 * wave + (lane >> 2);          // rows 32w..32w+15
  const int sq    = (lane & 3) ^ ((lane >> 3) & 3);   // swizzled global chunk
  const u16* Ag = A  + (size_t)(bm * 128 + srow0) * lda + sq * 8;
  const u16* Wg = Wt + (size_t)(bn * 128 + srow0) * ldw + sq * 8;
  u16* lA = sA + wave * 1024;   // 32 rows * 32 u16
  u16* lB = sB + wave * 1024;

  f32x4 acc[4][4] = {};

  for (int k0 = 0; k0 < K; k0 += 32) {
    __syncthreads();
    gload16(Ag + k0, lA);
    gload16(Ag + (size_t)16 * lda + k0, lA + 512);
    gload16(Wg + k0, lB);
    gload16(Wg + (size_t)16 * ldw + k0, lB + 512);
    __syncthreads();

    short8 a[4], b[4];
#pragma unroll
    for (int i = 0; i < 4; ++i) {
      const int r = wm + i * 16 + lrow;
      a[i] = *(const short8*)(sA + r * 32 + swz(r, lq) * 8);
    }
#pragma unroll
    for (int i = 0; i < 4; ++i) {
      const int r = wn + i * 16 + lrow;
      b[i] = *(const short8*)(sB + r * 32 + swz(r, lq) * 8);
    }

#pragma unroll
    for (int mi = 0; mi < 4; ++mi)
#pragma unroll
      for (int ni = 0; ni < 4; ++ni)
        acc[mi][ni] = __builtin_amdgcn_mfma_f32_16x16x32_bf16(a[mi], b[ni], acc[mi][ni], 0, 0, 0);
  }

#pragma unroll
  for (int ni = 0; ni < 4; ++ni) {
    const int col = bn * 128 + wn + ni * 16 + lrow;
    const float bv = bf2f(bias[col]);
#pragma unroll
    for (int mi = 0; mi < 4; ++mi) {
#pragma unroll
      for (int r = 0; r < 4; ++r) {
        const int row = bm * 128 + wm + mi * 16 + lq * 4 + r;
        float v = acc[mi][ni][r] + bv;
        if (ELU) v = elu_f(v);
        C[(size_t)row * ldc + col_off + col] = f2bf(v);
      }
    }
  }
}

// ---------------------------------------------------------------------------
// gating layer 3 + softmax: omega[B,5] fp32 = softmax(g2[B,128]@gw3 + gb3)
// ---------------------------------------------------------------------------
__global__ __launch_bounds__(256) void gating3_kernel(
    const u16* __restrict__ g2, const u16* __restrict__ gw3c,
    const u16* __restrict__ gb3c, float* __restrict__ omega)
{
  const int wid  = (blockIdx.x << 2) + (threadIdx.x >> 6);
  const int lane = threadIdx.x & 63;
  const u32 gp = *(const u32*)(g2 + (size_t)wid * 128 + lane * 2);
  const float x0 = bf2f((u16)(gp & 0xffffu));
  const float x1 = bf2f((u16)(gp >> 16));
  float acc[5];
#pragma unroll
  for (int e = 0; e < 5; ++e)
    acc[e] = x0 * bf2f(gw3c[(lane * 2) * 5 + e]) + x1 * bf2f(gw3c[(lane * 2 + 1) * 5 + e]);
#pragma unroll
  for (int off = 1; off < 64; off <<= 1) {
#pragma unroll
    for (int e = 0; e < 5; ++e) acc[e] += __shfl_xor(acc[e], off);
  }
  if (lane == 0) {
    float t[5], m = -1e30f;
#pragma unroll
    for (int e = 0; e < 5; ++e) { t[e] = acc[e] + bf2f(gb3c[e]); m = fmaxf(m, t[e]); }
    float s = 0.f;
#pragma unroll
    for (int e = 0; e < 5; ++e) { t[e] = expf(t[e] - m); s += t[e]; }
    const float inv = 1.f / s;
#pragma unroll
    for (int e = 0; e < 5; ++e) omega[(size_t)wid * 5 + e] = t[e] * inv;
  }
}

// ---------------------------------------------------------------------------
// MoE GEMM: out[b,n] = act( sum_e omega[b,e] * ((A@W_e)[n] + bias_e[n]) )
// Block tile 128x64. 4 waves as 2(M)x2(N): wave tile 64x32 -> per expert
// 4x2 MFMA 16x16x32, acc[5][4][2] = 160 VGPRs (needs the (256,2) bound —
// round 5 spilled to scratch at the default occupancy target).
// LDS fragment reads: (4 A + 10 B)/wave/K-step for 40 MFMAs = 0.35 rd/MFMA
// (was 0.6 at 32x32). A tile staged once, reused by all 5 experts.
// ---------------------------------------------------------------------------
template<bool ELU>
__global__ __launch_bounds__(256, 2) void moe_gemm(
    const u16* __restrict__ A, int lda,
    const u16* __restrict__ Wt, int ldw, long wstride_e,
    const u16* __restrict__ bias, int bias_n,
    const float* __restrict__ omega,
    void* __restrict__ C, int ldc, int col_off, int n_store, int K,
    const int* __restrict__ flagp, int is_final)
{
  __shared__ __align__(16) u16 sA[128 * 32];       // 8 KB
  __shared__ __align__(16) u16 sW[5][64 * 32];     // 20 KB
  __shared__ float som[128 * 5];
  __shared__ float sbias[5][64];

  const int tid  = threadIdx.x;
  const int bm   = blockIdx.x, bn = blockIdx.y;
  const int lane = tid & 63, wave = tid >> 6;
  const int wm = (wave & 1) * 64, wn = (wave >> 1) * 32;
  const int lrow = lane & 15, lq = lane >> 4;
  const int f32out = is_final ? *flagp : 0;

  for (int t = tid; t < 960; t += 256) {   // 640 som + 320 sbias
    if (t < 640) {
      som[t] = omega[(size_t)(bm * 128) * 5 + t];
    } else {
      const int j = t - 640;
      const int e = j >> 6, c = j & 63;
      const int col = bn * 64 + c;
      sbias[e][c] = (col < bias_n) ? bf2f(bias[(size_t)e * bias_n + col]) : 0.f;
    }
  }

  // A staging: wave w covers rows 32w..32w+31 (2 DMAs); W: rows 16w..16w+15
  // of each expert tile (5 DMAs). Patterns identical to round-4 (validated).
  const int sq = (lane & 3) ^ ((lane >> 3) & 3);
  const int srowA = 32 * wave + (lane >> 2);
  const int srowW = 16 * wave + (lane >> 2);
  const u16* Ag = A  + (size_t)(bm * 128 + srowA) * lda + sq * 8;
  const u16* Wg = Wt + (size_t)(bn * 64 + srowW) * ldw + sq * 8;
  u16* lA = sA + wave * 1024;       // 32 rows * 32 u16
  const int lWoff = wave * 512;     // 16 rows * 32 u16

  f32x4 acc[5][4][2] = {};

  for (int k0 = 0; k0 < K; k0 += 32) {
    __syncthreads();
    gload16(Ag + k0, lA);
    gload16(Ag + (size_t)16 * lda + k0, lA + 512);
#pragma unroll
    for (int e = 0; e < 5; ++e)
      gload16(Wg + e * wstride_e + k0, sW[e] + lWoff);
    __syncthreads();

    short8 a[4];
#pragma unroll
    for (int i = 0; i < 4; ++i) {
      const int r = wm + i * 16 + lrow;
      a[i] = *(const short8*)(sA + r * 32 + swz(r, lq) * 8);
    }
    const int rb0 = wn + lrow, rb1 = rb0 + 16;
    const int ob0 = rb0 * 32 + swz(rb0, lq) * 8;
    const int ob1 = rb1 * 32 + swz(rb1, lq) * 8;
#pragma unroll
    for (int e = 0; e < 5; ++e) {
      short8 b0 = *(const short8*)(sW[e] + ob0);
      short8 b1 = *(const short8*)(sW[e] + ob1);
#pragma unroll
      for (int mi = 0; mi < 4; ++mi) {
        acc[e][mi][0] = __builtin_amdgcn_mfma_f32_16x16x32_bf16(a[mi], b0, acc[e][mi][0], 0, 0, 0);
        acc[e][mi][1] = __builtin_amdgcn_mfma_f32_16x16x32_bf16(a[mi], b1, acc[e][mi][1], 0, 0, 0);
      }
    }
  }

#pragma unroll
  for (int mi = 0; mi < 4; ++mi) {
#pragma unroll
    for (int r = 0; r < 4; ++r) {
      const int rl = wm + mi * 16 + lq * 4 + r;       // row in block tile
      const int row = bm * 128 + rl;
      float om[5];
#pragma unroll
      for (int e = 0; e < 5; ++e) om[e] = som[rl * 5 + e];
#pragma unroll
      for (int ni = 0; ni < 2; ++ni) {
        const int c = wn + ni * 16 + lrow;            // col in block tile
        const int col = bn * 64 + c;
        if (col < n_store) {
          float v = 0.f;
#pragma unroll
          for (int e = 0; e < 5; ++e) v += om[e] * (acc[e][mi][ni][r] + sbias[e][c]);
          if (ELU) v = elu_f(v);
          const size_t idx = (size_t)row * ldc + col_off + col;
          if (f32out) ((float*)C)[idx] = v;
          else        ((u16*)C)[idx]   = f2bf(v);
        }
      }
    }
  }
}

// ---------------------------------------------------------------------------
extern "C" void kernel_launch(void* const* d_in, const int* in_sizes, int n_in,
                              void* d_out, int out_size, void* d_ws, size_t ws_size,
                              hipStream_t stream)
{
  const void* z    = d_in[0];
  const void* pprev= d_in[1];
  const void* I    = d_in[2];
  const void* gw1  = d_in[3];
  const void* gb1  = d_in[4];
  const void* gw2  = d_in[5];
  const void* gb2  = d_in[6];
  const void* gw3  = d_in[7];
  const void* gb3  = d_in[8];
  const void* iw1  = d_in[9];
  const void* ib1  = d_in[10];
  const void* iw2  = d_in[11];
  const void* ib2  = d_in[12];
  const void* iw3  = d_in[13];
  const void* ib3  = d_in[14];
  const void* wl1  = d_in[15];
  const void* bl1  = d_in[16];
  const void* wl2  = d_in[17];
  const void* bl2  = d_in[18];
  const void* wl3  = d_in[19];
  const void* bl3  = d_in[20];

  char* base = (char*)d_ws;
  size_t off = 0;
  auto alloc = [&](size_t bytes) -> void* {
    void* p = base + off;
    off = (off + bytes + 255) & ~(size_t)255;
    return p;
  };

  const size_t B = BATCH;
  int* flagp   = (int*)alloc(256);
  u16* h0      = (u16*)alloc(B * 832 * 2);   // [z | p_prev | ienc | pad0]
  u16* h1c     = (u16*)alloc(B * 288 * 2);   // [z | h1]
  u16* h2c     = (u16*)alloc(B * 288 * 2);   // [z | h2]
  u16* i1      = (u16*)alloc(B * 256 * 2);
  u16* i2      = (u16*)alloc(B * 256 * 2);
  float* omega = (float*)alloc(B * 5 * 4);
  u16* Ibf     = (u16*)alloc(B * 2048 * 2);
  u16* smallc  = (u16*)alloc(7100 * 2);
  u16* iw1t = (u16*)alloc((size_t)256 * 2048 * 2);
  u16* iw2t = (u16*)alloc((size_t)256 * 256 * 2);
  u16* iw3t = (u16*)alloc((size_t)256 * 256 * 2);
  u16* gw1t = (u16*)alloc((size_t)256 * 576 * 2);
  u16* gw2t = (u16*)alloc((size_t)128 * 256 * 2);
  u16* wl1t = (u16*)alloc((size_t)5 * 256 * 832 * 2);
  u16* wl2t = (u16*)alloc((size_t)5 * 256 * 288 * 2);
  u16* wl3t = (u16*)alloc((size_t)5 * 576 * 288 * 2);
  u16* g1 = i1;  // INet temporaries dead by gating time
  u16* g2 = i2;
  (void)in_sizes; (void)n_in; (void)out_size; (void)ws_size;

  u16* ib1c = smallc + 0,   *ib2c = smallc + 256, *ib3c = smallc + 512;
  u16* gb1c = smallc + 768, *gb2c = smallc + 1024, *gb3c = smallc + 1152;
  u16* gw3c = smallc + 1280;
  u16* bl1c = smallc + 1920, *bl2c = smallc + 3200, *bl3c = smallc + 4480;

  // ---- dtype detect + canonicalize ----
  detect_dtype<<<1, 256, 0, stream>>>((const u32*)z, flagp);
  prep_kernel<<<dim3(4, BATCH), 256, 0, stream>>>(z, pprev, flagp, h0, h1c, h2c,
      ib1, ib2, ib3, gb1, gb2, gb3, gw3, bl1, bl2, bl3, smallc);
  convert_I<<<4096, 256, 0, stream>>>(I, flagp, Ibf);
  transpose_all<<<3072, 256, 0, stream>>>(flagp,
      iw1, iw2, iw3, gw1, gw2, wl1, wl2, wl3,
      iw1t, iw2t, iw3t, gw1t, gw2t, wl1t, wl2t, wl3t);

  // ---- INet: I(2048) -> 256 -> 256 -> 256, into h0 cols 556..811 ----
  gemm128<true><<<dim3(BATCH/128, 2), 256, 0, stream>>>(Ibf, 2048, iw1t, 2048, ib1c, i1, 256, 0,   2048);
  gemm128<true><<<dim3(BATCH/128, 2), 256, 0, stream>>>(i1,  256,  iw2t, 256,  ib2c, i2, 256, 0,   256);
  gemm128<true><<<dim3(BATCH/128, 2), 256, 0, stream>>>(i2,  256,  iw3t, 256,  ib3c, h0, 832, 556, 256);

  // ---- Gating: [z|p_prev](556, padded 576) -> 256 -> 128 -> softmax(5) ----
  gemm128<true><<<dim3(BATCH/128, 2), 256, 0, stream>>>(h0, 832, gw1t, 576, gb1c, g1, 256, 0, 576);
  gemm128<true><<<dim3(BATCH/128, 1), 256, 0, stream>>>(g1, 256, gw2t, 256, gb2c, g2, 128, 0, 256);
  gating3_kernel<<<BATCH/4, 256, 0, stream>>>(g2, gw3c, gb3c, omega);

  // ---- MoE layers (block 128x64) ----
  moe_gemm<true><<<dim3(BATCH/128, 4), 256, 0, stream>>>(
      h0, 832, wl1t, 832, (long)256 * 832, bl1c, 256, omega, h1c, 288, 32, 256, 832, flagp, 0);
  moe_gemm<true><<<dim3(BATCH/128, 4), 256, 0, stream>>>(
      h1c, 288, wl2t, 288, (long)256 * 288, bl2c, 256, omega, h2c, 288, 32, 256, 288, flagp, 0);
  moe_gemm<false><<<dim3(BATCH/128, 9), 256, 0, stream>>>(
      h2c, 288, wl3t, 288, (long)576 * 288, bl3c, 524, omega, d_out, 524, 0, 524, 288, flagp, 1);
}